// Round 8
// baseline (6871.429 us; speedup 1.0000x reference)
//
#include <hip/hip_runtime.h>

typedef __attribute__((ext_vector_type(4))) float f32x4;
typedef __attribute__((ext_vector_type(8))) short short8;

#define LN_EPS 1e-5f

__device__ __forceinline__ float bf2f(short x) {
  union { unsigned u; float f; } c;
  c.u = ((unsigned)(unsigned short)x) << 16;
  return c.f;
}
__device__ __forceinline__ short f2b(float f) {
  union { float f; unsigned u; } c; c.f = f;
  unsigned r = (c.u + 0x7fffu + ((c.u >> 16) & 1u)) >> 16;
  return (short)r;
}

// ---------------- f32 -> bf16 convert (8 elems / thread) ----------------
__global__ __launch_bounds__(256) void cvt_kernel(const float* __restrict__ src,
                                                  short* __restrict__ dst, int n8) {
  int idx = blockIdx.x * 256 + threadIdx.x;
  int stride = gridDim.x * 256;
  for (int c = idx; c < n8; c += stride) {
    const f32x4* s = (const f32x4*)(src + (size_t)c * 8);
    f32x4 v0 = s[0], v1 = s[1];
    short8 o;
    o[0] = f2b(v0.x); o[1] = f2b(v0.y); o[2] = f2b(v0.z); o[3] = f2b(v0.w);
    o[4] = f2b(v1.x); o[5] = f2b(v1.y); o[6] = f2b(v1.z); o[7] = f2b(v1.w);
    *(short8*)(dst + (size_t)c * 8) = o;
  }
}

__global__ __launch_bounds__(256) void pack_bias(const float* __restrict__ bq,
                                                 const float* __restrict__ bk,
                                                 const float* __restrict__ bv,
                                                 float* __restrict__ dst) {
  int t = blockIdx.x * 256 + threadIdx.x;
  if (t < 1024) { dst[t] = bq[t]; dst[1024 + t] = bk[t]; dst[2048 + t] = bv[t]; }
}

__device__ __forceinline__ void gload16(const short* g, const short* l) {
  __builtin_amdgcn_global_load_lds((const __attribute__((address_space(1))) unsigned int*)g,
                                   (__attribute__((address_space(3))) unsigned int*)l,
                                   16, 0, 0);
}

// ---------------- GEMM: C[M,N] = A[M,1024] * W[N,1024]^T (+ epilogue) ----------------
// 256x256 tile, BK=64, 16 K-tiles. 512 threads (8 waves 2Mx4N), per-wave out 128x64.
// KEY CHANGE (r8): B never goes through LDS — W is L2-resident (6MB), each wave
// loads its 8 B-frags per K-tile global->reg one tile ahead (reg dbuf). LDS = A only,
// dbuf 2 x 32KB = 64KB -> 2 blocks/CU (16 waves): cross-block overlap hides barriers.
// One s_barrier + lgkmcnt(0) + vmcnt(0) per K-tile; all waited loads were issued a
// full K-tile (~2500cy) earlier. XOR-8 A swizzle (verified 0 conflicts).
template <int MODE>  // 0: out bf16 ldc=N, bias   1: out f32 ldc=N, bias+resid
__global__ __launch_bounds__(512, 4) void gemm256(
    const short* __restrict__ A, const short* __restrict__ W,
    const float* __restrict__ bias, const float* __restrict__ resid,
    void* __restrict__ Cptr, int N) {
  __shared__ __align__(16) short lds[32768];  // A dbuf: buf p at p*16384 shorts

  const int tid = threadIdx.x;
  const int w = tid >> 6, l = tid & 63;
  const int wr = w >> 2, wc = w & 3;
  const int r0 = l & 15, hk = l >> 4;

  // XCD swizzle (grid % 8 == 0 here)
  const int q8 = gridDim.x >> 3;
  const int wg = (blockIdx.x & 7) * q8 + (blockIdx.x >> 3);
  const int nbx = N >> 8;
  const int mb = wg / nbx, nb = wg - mb * nbx;
  const int m0 = mb << 8, n0 = nb << 8;

  // ---- A staging: per K-tile 256 rows x 64 shorts (32KB); thread covers 16B chunks
  // in 4 row-bands of 64; phys chunk tid&7, source col inverse-swizzled.
  const int srow = tid >> 3;                           // 0..63
  const int colsh = (((tid & 7) ^ (srow & 7)) << 3);   // inv-swizzled col (shorts)
  const short* gA0 = A + (size_t)(m0 + srow) * 1024 + colsh;
  const short* gA1 = gA0 + (size_t)64 * 1024;
  const short* gA2 = gA0 + (size_t)128 * 1024;
  const short* gA3 = gA0 + (size_t)192 * 1024;
  const int wofs = w * 512;  // wave-uniform LDS dest (shorts); lane*16B added by HW

#define STAGE_A(KT) do { const int qb_ = ((KT) & 1) * 16384, ko_ = (KT) * 64;  \
    gload16(gA0 + ko_, &lds[qb_ + wofs]);                                      \
    gload16(gA1 + ko_, &lds[qb_ + 4096 + wofs]);                               \
    gload16(gA2 + ko_, &lds[qb_ + 8192 + wofs]);                               \
    gload16(gA3 + ko_, &lds[qb_ + 12288 + wofs]); } while (0)

  // ---- B direct from global: lane (r0,hk) of wave-col wc covers W row
  // n0 + wc*64 + j*16 + r0, 16B chunk at k = kt*64 + ks*32 + hk*8.
  const short* gBb = W + (size_t)(n0 + wc * 64 + r0) * 1024 + hk * 8;

#define LOADB(KT, BV) do {                                                     \
    _Pragma("unroll")                                                          \
    for (int j_ = 0; j_ < 4; ++j_) {                                           \
      BV[j_][0] = *(const short8*)&gBb[j_ * 16384 + (KT) * 64];                \
      BV[j_][1] = *(const short8*)&gBb[j_ * 16384 + (KT) * 64 + 32];           \
    } } while (0)

  // ---- A fragment read offsets: phys chunk = (ks*4+hk) ^ (r0&7)
  const int swz = r0 & 7;
  const int ck0 = (hk ^ swz) * 8;
  const int ck1 = ((hk ^ 4) ^ swz) * 8;
  const int ar = (wr * 128 + r0) * 64;  // + buf*16384, + i*1024 per 16-row step

#define LDS8(ofs) (*(const short8*)&lds[(ofs)])

#define ITER(T, BC, BN) do {                                                   \
    const int qb_ = ((T) & 1) * 16384;                                         \
    if ((T) < 15) { STAGE_A((T) + 1); LOADB((T) + 1, BN); }                    \
    short8 av0[4], av1[4];                                                     \
    _Pragma("unroll")                                                          \
    for (int i_ = 0; i_ < 4; ++i_) {                                           \
      av0[i_] = LDS8(qb_ + ar + i_ * 1024 + ck0);                              \
      av1[i_] = LDS8(qb_ + ar + i_ * 1024 + ck1);                              \
    }                                                                          \
    __builtin_amdgcn_s_setprio(1);                                             \
    _Pragma("unroll")                                                          \
    for (int i_ = 0; i_ < 4; ++i_)                                             \
      _Pragma("unroll")                                                        \
      for (int j_ = 0; j_ < 4; ++j_) {                                         \
        acc[i_][j_] = __builtin_amdgcn_mfma_f32_16x16x32_bf16(av0[i_], BC[j_][0], acc[i_][j_], 0, 0, 0); \
        acc[i_][j_] = __builtin_amdgcn_mfma_f32_16x16x32_bf16(av1[i_], BC[j_][1], acc[i_][j_], 0, 0, 0); \
      }                                                                        \
    __builtin_amdgcn_s_setprio(0);                                             \
    _Pragma("unroll")                                                          \
    for (int i_ = 0; i_ < 4; ++i_) {                                           \
      av0[i_] = LDS8(qb_ + ar + (4 + i_) * 1024 + ck0);                        \
      av1[i_] = LDS8(qb_ + ar + (4 + i_) * 1024 + ck1);                        \
    }                                                                          \
    __builtin_amdgcn_s_setprio(1);                                             \
    _Pragma("unroll")                                                          \
    for (int i_ = 0; i_ < 4; ++i_)                                             \
      _Pragma("unroll")                                                        \
      for (int j_ = 0; j_ < 4; ++j_) {                                         \
        acc[4 + i_][j_] = __builtin_amdgcn_mfma_f32_16x16x32_bf16(av0[i_], BC[j_][0], acc[4 + i_][j_], 0, 0, 0); \
        acc[4 + i_][j_] = __builtin_amdgcn_mfma_f32_16x16x32_bf16(av1[i_], BC[j_][1], acc[4 + i_][j_], 0, 0, 0); \
      }                                                                        \
    __builtin_amdgcn_s_setprio(0);                                             \
    asm volatile("s_waitcnt lgkmcnt(0)" ::: "memory");                         \
    if ((T) < 15) { asm volatile("s_waitcnt vmcnt(0)" ::: "memory"); }         \
    __builtin_amdgcn_s_barrier();                                              \
  } while (0)

  f32x4 acc[8][4];
#pragma unroll
  for (int i = 0; i < 8; ++i)
#pragma unroll
    for (int j = 0; j < 4; ++j) acc[i][j] = (f32x4)(0.f);

  short8 b0[4][2], b1[4][2];

  // prologue: tile 0 -> buf 0 + B(0) regs
  STAGE_A(0);
  LOADB(0, b0);
  asm volatile("s_waitcnt vmcnt(0)" ::: "memory");
  __builtin_amdgcn_s_barrier();

#pragma unroll 1
  for (int u = 0; u < 8; ++u) {
    ITER(2 * u,     b0, b1);
    ITER(2 * u + 1, b1, b0);
  }
#undef STAGE_A
#undef LOADB
#undef LDS8
#undef ITER

  const int crow = m0 + wr * 128 + hk * 4;
  const int ccol = n0 + wc * 64 + r0;
  if (MODE == 0) {
    short* C = (short*)Cptr;
#pragma unroll
    for (int j = 0; j < 4; ++j) {
      float bj = bias[ccol + j * 16];
#pragma unroll
      for (int i = 0; i < 8; ++i) {
        size_t base = (size_t)(crow + i * 16) * N + (ccol + j * 16);
#pragma unroll
        for (int rr = 0; rr < 4; ++rr)
          C[base + (size_t)rr * N] = f2b(acc[i][j][rr] + bj);
      }
    }
  } else {
    float* C = (float*)Cptr;
#pragma unroll
    for (int j = 0; j < 4; ++j) {
      float bj = bias[ccol + j * 16];
#pragma unroll
      for (int i = 0; i < 8; ++i) {
        size_t base = (size_t)(crow + i * 16) * N + (ccol + j * 16);
#pragma unroll
        for (int rr = 0; rr < 4; ++rr)
          C[base + (size_t)rr * N] =
              acc[i][j][rr] + bj + resid[base + (size_t)rr * N];
      }
    }
  }
}

// ---------------- attention: 1 block per b, 4 waves, 2 heads/wave ----------------
__global__ __launch_bounds__(256) void attn_kernel(
    const short* __restrict__ qkv, const float* __restrict__ prior,
    const float* __restrict__ mask, short* __restrict__ out) {
  __shared__ short sq[8 * 3080];  // rows padded +8 shorts to break bank conflicts
  const int tid = threadIdx.x;
  const int b = blockIdx.x;
  for (int c = tid; c < 3072; c += 256) {
    int row = c / 384;
    int cc = c - row * 384;
    *(short8*)&sq[row * 3080 + cc * 8] =
        *(const short8*)&qkv[((size_t)b * 8 + row) * 3072 + cc * 8];
  }
  __syncthreads();
  const int l = tid & 63, w = tid >> 6;
  const int i = l >> 3, j = l & 7;
  const float pv = prior[l];
  const float mm = mask[b * 8 + i] * mask[b * 8 + j];
#pragma unroll
  for (int hh = 0; hh < 2; ++hh) {
    const int h = w + hh * 4;
    const short* Qr = &sq[i * 3080 + h * 128];
    const short* Kr = &sq[j * 3080 + 1024 + h * 128];
    float s = 0.f;
#pragma unroll
    for (int c = 0; c < 16; ++c) {
      short8 qa = *(const short8*)&Qr[c * 8];
      short8 ka = *(const short8*)&Kr[c * 8];
#pragma unroll
      for (int e = 0; e < 8; ++e) s += bf2f(qa[e]) * bf2f(ka[e]);
    }
    s = s * 0.08838834764831843f + pv;  // 1/sqrt(128)
    if (!(mm > 0.f)) s = -__builtin_inff();
    float mx = s;
#pragma unroll
    for (int off = 1; off < 8; off <<= 1) mx = fmaxf(mx, __shfl_xor(mx, off));
    float e = __expf(s - mx);
    float sum = e;
#pragma unroll
    for (int off = 1; off < 8; off <<= 1) sum += __shfl_xor(sum, off);
    float p = e / sum;
    float o[16];
#pragma unroll
    for (int t = 0; t < 16; ++t) o[t] = 0.f;
#pragma unroll
    for (int jj = 0; jj < 8; ++jj) {
      float pj = __shfl(p, i * 8 + jj);
      const short* Vr = &sq[jj * 3080 + 2048 + h * 128 + j * 16];
      short8 v0 = *(const short8*)&Vr[0];
      short8 v1 = *(const short8*)&Vr[8];
#pragma unroll
      for (int e2 = 0; e2 < 8; ++e2) {
        o[e2] += pj * bf2f(v0[e2]);
        o[8 + e2] += pj * bf2f(v1[e2]);
      }
    }
    short8 o0, o1;
#pragma unroll
    for (int e2 = 0; e2 < 8; ++e2) { o0[e2] = f2b(o[e2]); o1[e2] = f2b(o[8 + e2]); }
    short* dst = out + ((size_t)(b * 8 + i)) * 1024 + h * 128 + j * 16;
    *(short8*)dst = o0;
    *(short8*)(dst + 8) = o1;
  }
}

// ---------------- LayerNorm in-place, 1 wave per row ----------------
__global__ __launch_bounds__(256) void ln_kernel(float* __restrict__ io,
                                                 const float* __restrict__ gamma,
                                                 const float* __restrict__ beta) {
  const int l = threadIdx.x & 63, w = threadIdx.x >> 6;
  float* p = io + ((size_t)blockIdx.x * 4 + w) * 1024;
  f32x4 v[4];
  float s = 0.f;
#pragma unroll
  for (int c = 0; c < 4; ++c) {
    v[c] = *(const f32x4*)(p + (c * 64 + l) * 4);
    s += v[c][0] + v[c][1] + v[c][2] + v[c][3];
  }
#pragma unroll
  for (int off = 32; off > 0; off >>= 1) s += __shfl_xor(s, off);
  const float mu = s * (1.f / 1024.f);
  float s2 = 0.f;
#pragma unroll
  for (int c = 0; c < 4; ++c)
#pragma unroll
    for (int e = 0; e < 4; ++e) { float d = v[c][e] - mu; s2 += d * d; }
#pragma unroll
  for (int off = 32; off > 0; off >>= 1) s2 += __shfl_xor(s2, off);
  const float rstd = rsqrtf(s2 * (1.f / 1024.f) + LN_EPS);
#pragma unroll
  for (int c = 0; c < 4; ++c) {
    f32x4 g = *(const f32x4*)(gamma + (c * 64 + l) * 4);
    f32x4 bt = *(const f32x4*)(beta + (c * 64 + l) * 4);
    f32x4 ov;
#pragma unroll
    for (int e = 0; e < 4; ++e) ov[e] = (v[c][e] - mu) * rstd * g[e] + bt[e];
    *(f32x4*)(p + (c * 64 + l) * 4) = ov;
  }
}

extern "C" void kernel_launch(void* const* d_in, const int* in_sizes, int n_in,
                              void* d_out, int out_size, void* d_ws, size_t ws_size,
                              hipStream_t stream) {
  const float* x     = (const float*)d_in[0];
  const float* mask  = (const float*)d_in[1];
  const float* wq    = (const float*)d_in[2];
  const float* bq    = (const float*)d_in[3];
  const float* wk    = (const float*)d_in[4];
  const float* bk    = (const float*)d_in[5];
  const float* wv    = (const float*)d_in[6];
  const float* bv    = (const float*)d_in[7];
  const float* wo    = (const float*)d_in[8];
  const float* bo    = (const float*)d_in[9];
  const float* prior = (const float*)d_in[10];
  const float* gamma = (const float*)d_in[11];
  const float* beta  = (const float*)d_in[12];

  char* ws = (char*)d_ws;
  short* qkv  = (short*)(ws);                    // [65536][3072] bf16 (402.7 MB)
  short* xb   = (short*)(ws + 402653184L);       // [65536][1024] bf16; reused as attn_out
  short* wall = (short*)(ws + 536870912L);       // [3072][1024] bf16 (Wq|Wk|Wv)
  short* wob  = (short*)(ws + 543162368L);       // [1024][1024] bf16
  float* ball = (float*)(ws + 545259520L);       // [3072] f32

  cvt_kernel<<<2048, 256, 0, stream>>>(x, xb, 8388608);
  cvt_kernel<<<512, 256, 0, stream>>>(wq, wall,           131072);
  cvt_kernel<<<512, 256, 0, stream>>>(wk, wall + 1048576, 131072);
  cvt_kernel<<<512, 256, 0, stream>>>(wv, wall + 2097152, 131072);
  cvt_kernel<<<512, 256, 0, stream>>>(wo, wob,            131072);
  pack_bias<<<4, 256, 0, stream>>>(bq, bk, bv, ball);

  // QKV projection: [65536,3072] = xb @ Wall^T + ball   (256x12 = 3072 blocks)
  gemm256<0><<<3072, 512, 0, stream>>>(xb, wall, ball, nullptr, qkv, 3072);
  // attention (writes into xb, free after QKV GEMM)
  attn_kernel<<<8192, 256, 0, stream>>>(qkv, prior, mask, xb);
  // O projection + bias + residual -> d_out (f32)   (256x4 = 1024 blocks)
  gemm256<1><<<1024, 512, 0, stream>>>(xb, wob, bo, x, d_out, 1024);
  // LayerNorm in-place on d_out
  ln_kernel<<<16384, 256, 0, stream>>>((float*)d_out, gamma, beta);
}

// Round 9
// 1277.768 us; speedup vs baseline: 5.3777x; 5.3777x over previous
//
#include <hip/hip_runtime.h>

typedef __attribute__((ext_vector_type(4))) float f32x4;
typedef __attribute__((ext_vector_type(8))) short short8;

#define LN_EPS 1e-5f

__device__ __forceinline__ float bf2f(short x) {
  union { unsigned u; float f; } c;
  c.u = ((unsigned)(unsigned short)x) << 16;
  return c.f;
}
__device__ __forceinline__ short f2b(float f) {
  union { float f; unsigned u; } c; c.f = f;
  unsigned r = (c.u + 0x7fffu + ((c.u >> 16) & 1u)) >> 16;
  return (short)r;
}

// ---------------- f32 -> bf16 convert (8 elems / thread) ----------------
__global__ __launch_bounds__(256) void cvt_kernel(const float* __restrict__ src,
                                                  short* __restrict__ dst, int n8) {
  int idx = blockIdx.x * 256 + threadIdx.x;
  int stride = gridDim.x * 256;
  for (int c = idx; c < n8; c += stride) {
    const f32x4* s = (const f32x4*)(src + (size_t)c * 8);
    f32x4 v0 = s[0], v1 = s[1];
    short8 o;
    o[0] = f2b(v0.x); o[1] = f2b(v0.y); o[2] = f2b(v0.z); o[3] = f2b(v0.w);
    o[4] = f2b(v1.x); o[5] = f2b(v1.y); o[6] = f2b(v1.z); o[7] = f2b(v1.w);
    *(short8*)(dst + (size_t)c * 8) = o;
  }
}

__global__ __launch_bounds__(256) void pack_bias(const float* __restrict__ bq,
                                                 const float* __restrict__ bk,
                                                 const float* __restrict__ bv,
                                                 float* __restrict__ dst) {
  int t = blockIdx.x * 256 + threadIdx.x;
  if (t < 1024) { dst[t] = bq[t]; dst[1024 + t] = bk[t]; dst[2048 + t] = bv[t]; }
}

__device__ __forceinline__ void gload16(const short* g, const short* l) {
  __builtin_amdgcn_global_load_lds((const __attribute__((address_space(1))) unsigned int*)g,
                                   (__attribute__((address_space(3))) unsigned int*)l,
                                   16, 0, 0);
}

// ---------------- GEMM: C[M,N] = A[M,1024] * W[N,1024]^T (+ epilogue) ----------------
// 256x256 tile, BK=64, 16 K-tiles. 512 threads (8 waves 2Mx4N), per-wave out 128x64.
// B never goes through LDS — W is L2-resident (6MB): each wave loads its 8 B-frags
// per K-tile global->reg one tile ahead (reg dbuf). LDS = A only, dbuf 2x32KB = 64KB.
// One s_barrier + lgkmcnt(0) + vmcnt(0) per K-tile; the waited loads were issued a
// full 64-MFMA block (~2500cy) earlier. XOR-8 A swizzle (verified 0 conflicts).
// launch_bounds (512,2): 256-reg/thread budget — acc 128 AGPR + ~120 arch VGPR.
// (r8's (512,4) capped at 128 regs -> accumulator spilled to scratch, 20GB HBM.)
template <int MODE>  // 0: out bf16 ldc=N, bias   1: out f32 ldc=N, bias+resid
__global__ __launch_bounds__(512, 2) void gemm256(
    const short* __restrict__ A, const short* __restrict__ W,
    const float* __restrict__ bias, const float* __restrict__ resid,
    void* __restrict__ Cptr, int N) {
  __shared__ __align__(16) short lds[32768];  // A dbuf: buf p at p*16384 shorts

  const int tid = threadIdx.x;
  const int w = tid >> 6, l = tid & 63;
  const int wr = w >> 2, wc = w & 3;
  const int r0 = l & 15, hk = l >> 4;

  // XCD swizzle (grid % 8 == 0 here)
  const int q8 = gridDim.x >> 3;
  const int wg = (blockIdx.x & 7) * q8 + (blockIdx.x >> 3);
  const int nbx = N >> 8;
  const int mb = wg / nbx, nb = wg - mb * nbx;
  const int m0 = mb << 8, n0 = nb << 8;

  // ---- A staging: per K-tile 256 rows x 64 shorts (32KB); thread covers 16B chunks
  // in 4 row-bands of 64; phys chunk tid&7, source col inverse-swizzled.
  const int srow = tid >> 3;                           // 0..63
  const int colsh = (((tid & 7) ^ (srow & 7)) << 3);   // inv-swizzled col (shorts)
  const short* gA0 = A + (size_t)(m0 + srow) * 1024 + colsh;
  const short* gA1 = gA0 + (size_t)64 * 1024;
  const short* gA2 = gA0 + (size_t)128 * 1024;
  const short* gA3 = gA0 + (size_t)192 * 1024;
  const int wofs = w * 512;  // wave-uniform LDS dest (shorts); lane*16B added by HW

#define STAGE_A(KT) do { const int qb_ = ((KT) & 1) * 16384, ko_ = (KT) * 64;  \
    gload16(gA0 + ko_, &lds[qb_ + wofs]);                                      \
    gload16(gA1 + ko_, &lds[qb_ + 4096 + wofs]);                               \
    gload16(gA2 + ko_, &lds[qb_ + 8192 + wofs]);                               \
    gload16(gA3 + ko_, &lds[qb_ + 12288 + wofs]); } while (0)

  // ---- B direct from global: lane (r0,hk) of wave-col wc covers W row
  // n0 + wc*64 + j*16 + r0, 16B chunk at k = kt*64 + ks*32 + hk*8.
  const short* gBb = W + (size_t)(n0 + wc * 64 + r0) * 1024 + hk * 8;

#define LOADB(KT, BV) do {                                                     \
    _Pragma("unroll")                                                          \
    for (int j_ = 0; j_ < 4; ++j_) {                                           \
      BV[j_][0] = *(const short8*)&gBb[j_ * 16384 + (KT) * 64];                \
      BV[j_][1] = *(const short8*)&gBb[j_ * 16384 + (KT) * 64 + 32];           \
    } } while (0)

  // ---- A fragment read offsets: phys chunk = (ks*4+hk) ^ (r0&7)
  const int swz = r0 & 7;
  const int ck0 = (hk ^ swz) * 8;
  const int ck1 = ((hk ^ 4) ^ swz) * 8;
  const int ar = (wr * 128 + r0) * 64;  // + buf*16384, + i*1024 per 16-row step

#define LDS8(ofs) (*(const short8*)&lds[(ofs)])

#define ITER(T, BC, BN) do {                                                   \
    const int qb_ = ((T) & 1) * 16384;                                         \
    if ((T) < 15) { STAGE_A((T) + 1); LOADB((T) + 1, BN); }                    \
    short8 av0[4], av1[4];                                                     \
    _Pragma("unroll")                                                          \
    for (int i_ = 0; i_ < 4; ++i_) {                                           \
      av0[i_] = LDS8(qb_ + ar + i_ * 1024 + ck0);                              \
      av1[i_] = LDS8(qb_ + ar + i_ * 1024 + ck1);                              \
    }                                                                          \
    __builtin_amdgcn_s_setprio(1);                                             \
    _Pragma("unroll")                                                          \
    for (int i_ = 0; i_ < 4; ++i_)                                             \
      _Pragma("unroll")                                                        \
      for (int j_ = 0; j_ < 4; ++j_) {                                         \
        acc[i_][j_] = __builtin_amdgcn_mfma_f32_16x16x32_bf16(av0[i_], BC[j_][0], acc[i_][j_], 0, 0, 0); \
        acc[i_][j_] = __builtin_amdgcn_mfma_f32_16x16x32_bf16(av1[i_], BC[j_][1], acc[i_][j_], 0, 0, 0); \
      }                                                                        \
    __builtin_amdgcn_s_setprio(0);                                             \
    _Pragma("unroll")                                                          \
    for (int i_ = 0; i_ < 4; ++i_) {                                           \
      av0[i_] = LDS8(qb_ + ar + (4 + i_) * 1024 + ck0);                        \
      av1[i_] = LDS8(qb_ + ar + (4 + i_) * 1024 + ck1);                        \
    }                                                                          \
    __builtin_amdgcn_s_setprio(1);                                             \
    _Pragma("unroll")                                                          \
    for (int i_ = 0; i_ < 4; ++i_)                                             \
      _Pragma("unroll")                                                        \
      for (int j_ = 0; j_ < 4; ++j_) {                                         \
        acc[4 + i_][j_] = __builtin_amdgcn_mfma_f32_16x16x32_bf16(av0[i_], BC[j_][0], acc[4 + i_][j_], 0, 0, 0); \
        acc[4 + i_][j_] = __builtin_amdgcn_mfma_f32_16x16x32_bf16(av1[i_], BC[j_][1], acc[4 + i_][j_], 0, 0, 0); \
      }                                                                        \
    __builtin_amdgcn_s_setprio(0);                                             \
    asm volatile("s_waitcnt lgkmcnt(0)" ::: "memory");                         \
    if ((T) < 15) { asm volatile("s_waitcnt vmcnt(0)" ::: "memory"); }         \
    __builtin_amdgcn_s_barrier();                                              \
  } while (0)

  f32x4 acc[8][4];
#pragma unroll
  for (int i = 0; i < 8; ++i)
#pragma unroll
    for (int j = 0; j < 4; ++j) acc[i][j] = (f32x4)(0.f);

  short8 b0[4][2], b1[4][2];

  // prologue: tile 0 -> buf 0 + B(0) regs
  STAGE_A(0);
  LOADB(0, b0);
  asm volatile("s_waitcnt vmcnt(0)" ::: "memory");
  __builtin_amdgcn_s_barrier();

#pragma unroll 1
  for (int u = 0; u < 8; ++u) {
    ITER(2 * u,     b0, b1);
    ITER(2 * u + 1, b1, b0);
  }
#undef STAGE_A
#undef LOADB
#undef LDS8
#undef ITER

  const int crow = m0 + wr * 128 + hk * 4;
  const int ccol = n0 + wc * 64 + r0;
  if (MODE == 0) {
    short* C = (short*)Cptr;
#pragma unroll
    for (int j = 0; j < 4; ++j) {
      float bj = bias[ccol + j * 16];
#pragma unroll
      for (int i = 0; i < 8; ++i) {
        size_t base = (size_t)(crow + i * 16) * N + (ccol + j * 16);
#pragma unroll
        for (int rr = 0; rr < 4; ++rr)
          C[base + (size_t)rr * N] = f2b(acc[i][j][rr] + bj);
      }
    }
  } else {
    float* C = (float*)Cptr;
#pragma unroll
    for (int j = 0; j < 4; ++j) {
      float bj = bias[ccol + j * 16];
#pragma unroll
      for (int i = 0; i < 8; ++i) {
        size_t base = (size_t)(crow + i * 16) * N + (ccol + j * 16);
#pragma unroll
        for (int rr = 0; rr < 4; ++rr)
          C[base + (size_t)rr * N] =
              acc[i][j][rr] + bj + resid[base + (size_t)rr * N];
      }
    }
  }
}

// ---------------- attention: 1 block per b, 4 waves, 2 heads/wave ----------------
__global__ __launch_bounds__(256) void attn_kernel(
    const short* __restrict__ qkv, const float* __restrict__ prior,
    const float* __restrict__ mask, short* __restrict__ out) {
  __shared__ short sq[8 * 3080];  // rows padded +8 shorts to break bank conflicts
  const int tid = threadIdx.x;
  const int b = blockIdx.x;
  for (int c = tid; c < 3072; c += 256) {
    int row = c / 384;
    int cc = c - row * 384;
    *(short8*)&sq[row * 3080 + cc * 8] =
        *(const short8*)&qkv[((size_t)b * 8 + row) * 3072 + cc * 8];
  }
  __syncthreads();
  const int l = tid & 63, w = tid >> 6;
  const int i = l >> 3, j = l & 7;
  const float pv = prior[l];
  const float mm = mask[b * 8 + i] * mask[b * 8 + j];
#pragma unroll
  for (int hh = 0; hh < 2; ++hh) {
    const int h = w + hh * 4;
    const short* Qr = &sq[i * 3080 + h * 128];
    const short* Kr = &sq[j * 3080 + 1024 + h * 128];
    float s = 0.f;
#pragma unroll
    for (int c = 0; c < 16; ++c) {
      short8 qa = *(const short8*)&Qr[c * 8];
      short8 ka = *(const short8*)&Kr[c * 8];
#pragma unroll
      for (int e = 0; e < 8; ++e) s += bf2f(qa[e]) * bf2f(ka[e]);
    }
    s = s * 0.08838834764831843f + pv;  // 1/sqrt(128)
    if (!(mm > 0.f)) s = -__builtin_inff();
    float mx = s;
#pragma unroll
    for (int off = 1; off < 8; off <<= 1) mx = fmaxf(mx, __shfl_xor(mx, off));
    float e = __expf(s - mx);
    float sum = e;
#pragma unroll
    for (int off = 1; off < 8; off <<= 1) sum += __shfl_xor(sum, off);
    float p = e / sum;
    float o[16];
#pragma unroll
    for (int t = 0; t < 16; ++t) o[t] = 0.f;
#pragma unroll
    for (int jj = 0; jj < 8; ++jj) {
      float pj = __shfl(p, i * 8 + jj);
      const short* Vr = &sq[jj * 3080 + 2048 + h * 128 + j * 16];
      short8 v0 = *(const short8*)&Vr[0];
      short8 v1 = *(const short8*)&Vr[8];
#pragma unroll
      for (int e2 = 0; e2 < 8; ++e2) {
        o[e2] += pj * bf2f(v0[e2]);
        o[8 + e2] += pj * bf2f(v1[e2]);
      }
    }
    short8 o0, o1;
#pragma unroll
    for (int e2 = 0; e2 < 8; ++e2) { o0[e2] = f2b(o[e2]); o1[e2] = f2b(o[8 + e2]); }
    short* dst = out + ((size_t)(b * 8 + i)) * 1024 + h * 128 + j * 16;
    *(short8*)dst = o0;
    *(short8*)(dst + 8) = o1;
  }
}

// ---------------- LayerNorm in-place, 1 wave per row ----------------
__global__ __launch_bounds__(256) void ln_kernel(float* __restrict__ io,
                                                 const float* __restrict__ gamma,
                                                 const float* __restrict__ beta) {
  const int l = threadIdx.x & 63, w = threadIdx.x >> 6;
  float* p = io + ((size_t)blockIdx.x * 4 + w) * 1024;
  f32x4 v[4];
  float s = 0.f;
#pragma unroll
  for (int c = 0; c < 4; ++c) {
    v[c] = *(const f32x4*)(p + (c * 64 + l) * 4);
    s += v[c][0] + v[c][1] + v[c][2] + v[c][3];
  }
#pragma unroll
  for (int off = 32; off > 0; off >>= 1) s += __shfl_xor(s, off);
  const float mu = s * (1.f / 1024.f);
  float s2 = 0.f;
#pragma unroll
  for (int c = 0; c < 4; ++c)
#pragma unroll
    for (int e = 0; e < 4; ++e) { float d = v[c][e] - mu; s2 += d * d; }
#pragma unroll
  for (int off = 32; off > 0; off >>= 1) s2 += __shfl_xor(s2, off);
  const float rstd = rsqrtf(s2 * (1.f / 1024.f) + LN_EPS);
#pragma unroll
  for (int c = 0; c < 4; ++c) {
    f32x4 g = *(const f32x4*)(gamma + (c * 64 + l) * 4);
    f32x4 bt = *(const f32x4*)(beta + (c * 64 + l) * 4);
    f32x4 ov;
#pragma unroll
    for (int e = 0; e < 4; ++e) ov[e] = (v[c][e] - mu) * rstd * g[e] + bt[e];
    *(f32x4*)(p + (c * 64 + l) * 4) = ov;
  }
}

extern "C" void kernel_launch(void* const* d_in, const int* in_sizes, int n_in,
                              void* d_out, int out_size, void* d_ws, size_t ws_size,
                              hipStream_t stream) {
  const float* x     = (const float*)d_in[0];
  const float* mask  = (const float*)d_in[1];
  const float* wq    = (const float*)d_in[2];
  const float* bq    = (const float*)d_in[3];
  const float* wk    = (const float*)d_in[4];
  const float* bk    = (const float*)d_in[5];
  const float* wv    = (const float*)d_in[6];
  const float* bv    = (const float*)d_in[7];
  const float* wo    = (const float*)d_in[8];
  const float* bo    = (const float*)d_in[9];
  const float* prior = (const float*)d_in[10];
  const float* gamma = (const float*)d_in[11];
  const float* beta  = (const float*)d_in[12];

  char* ws = (char*)d_ws;
  short* qkv  = (short*)(ws);                    // [65536][3072] bf16 (402.7 MB)
  short* xb   = (short*)(ws + 402653184L);       // [65536][1024] bf16; reused as attn_out
  short* wall = (short*)(ws + 536870912L);       // [3072][1024] bf16 (Wq|Wk|Wv)
  short* wob  = (short*)(ws + 543162368L);       // [1024][1024] bf16
  float* ball = (float*)(ws + 545259520L);       // [3072] f32

  cvt_kernel<<<2048, 256, 0, stream>>>(x, xb, 8388608);
  cvt_kernel<<<512, 256, 0, stream>>>(wq, wall,           131072);
  cvt_kernel<<<512, 256, 0, stream>>>(wk, wall + 1048576, 131072);
  cvt_kernel<<<512, 256, 0, stream>>>(wv, wall + 2097152, 131072);
  cvt_kernel<<<512, 256, 0, stream>>>(wo, wob,            131072);
  pack_bias<<<4, 256, 0, stream>>>(bq, bk, bv, ball);

  // QKV projection: [65536,3072] = xb @ Wall^T + ball   (256x12 = 3072 blocks)
  gemm256<0><<<3072, 512, 0, stream>>>(xb, wall, ball, nullptr, qkv, 3072);
  // attention (writes into xb, free after QKV GEMM)
  attn_kernel<<<8192, 256, 0, stream>>>(qkv, prior, mask, xb);
  // O projection + bias + residual -> d_out (f32)   (256x4 = 1024 blocks)
  gemm256<1><<<1024, 512, 0, stream>>>(xb, wob, bo, x, d_out, 1024);
  // LayerNorm in-place on d_out
  ln_kernel<<<16384, 256, 0, stream>>>((float*)d_out, gamma, beta);
}

// Round 10
// 960.241 us; speedup vs baseline: 7.1559x; 1.3307x over previous
//
#include <hip/hip_runtime.h>

typedef __attribute__((ext_vector_type(4))) float f32x4;
typedef __attribute__((ext_vector_type(8))) short short8;

#define LN_EPS 1e-5f

__device__ __forceinline__ float bf2f(short x) {
  union { unsigned u; float f; } c;
  c.u = ((unsigned)(unsigned short)x) << 16;
  return c.f;
}
__device__ __forceinline__ short f2b(float f) {
  union { float f; unsigned u; } c; c.f = f;
  unsigned r = (c.u + 0x7fffu + ((c.u >> 16) & 1u)) >> 16;
  return (short)r;
}

// ---------------- f32 -> bf16 convert (8 elems / thread) ----------------
__global__ __launch_bounds__(256) void cvt_kernel(const float* __restrict__ src,
                                                  short* __restrict__ dst, int n8) {
  int idx = blockIdx.x * 256 + threadIdx.x;
  int stride = gridDim.x * 256;
  for (int c = idx; c < n8; c += stride) {
    const f32x4* s = (const f32x4*)(src + (size_t)c * 8);
    f32x4 v0 = s[0], v1 = s[1];
    short8 o;
    o[0] = f2b(v0.x); o[1] = f2b(v0.y); o[2] = f2b(v0.z); o[3] = f2b(v0.w);
    o[4] = f2b(v1.x); o[5] = f2b(v1.y); o[6] = f2b(v1.z); o[7] = f2b(v1.w);
    *(short8*)(dst + (size_t)c * 8) = o;
  }
}

// all 4 weight matrices in one launch: 4 x 131072 chunks of 8
__global__ __launch_bounds__(256) void cvt_w_kernel(
    const float* __restrict__ wq, const float* __restrict__ wk,
    const float* __restrict__ wv, const float* __restrict__ wo,
    short* __restrict__ wall, short* __restrict__ wob) {
  int c = blockIdx.x * 256 + threadIdx.x;
  int stride = gridDim.x * 256;
  for (; c < 524288; c += stride) {
    int seg = c >> 17, idx = c & 131071;
    const float* src = (seg == 0) ? wq : (seg == 1) ? wk : (seg == 2) ? wv : wo;
    short* dst = (seg == 3) ? wob : (wall + (size_t)seg * 1048576);
    const f32x4* s = (const f32x4*)(src + (size_t)idx * 8);
    f32x4 v0 = s[0], v1 = s[1];
    short8 o;
    o[0] = f2b(v0.x); o[1] = f2b(v0.y); o[2] = f2b(v0.z); o[3] = f2b(v0.w);
    o[4] = f2b(v1.x); o[5] = f2b(v1.y); o[6] = f2b(v1.z); o[7] = f2b(v1.w);
    *(short8*)(dst + (size_t)idx * 8) = o;
  }
}

__global__ __launch_bounds__(256) void pack_bias(const float* __restrict__ bq,
                                                 const float* __restrict__ bk,
                                                 const float* __restrict__ bv,
                                                 float* __restrict__ dst) {
  int t = blockIdx.x * 256 + threadIdx.x;
  if (t < 1024) { dst[t] = bq[t]; dst[1024 + t] = bk[t]; dst[2048 + t] = bv[t]; }
}

__device__ __forceinline__ void gload16(const short* g, const short* l) {
  __builtin_amdgcn_global_load_lds((const __attribute__((address_space(1))) unsigned int*)g,
                                   (__attribute__((address_space(3))) unsigned int*)l,
                                   16, 0, 0);
}

// ---------------- GEMM: C[M,N] = A[M,1024] * W[N,1024]^T (+ epilogue) ----------------
// r4 structure (best measured: 42.7% MfmaUtil): 256x256 tile, BK=64, 512 threads
// (8 waves 2Mx4N), LDS = 2dbuf x {A,B} x 16KB = 128KB. 4 phases per K-tile; counted
// vmcnt(8) ledger: during tile T stage tile T+2 into T's own buffer, B-halves at P3
// (dead after P2 reads), A-halves at P4 (dead after P3). At P1 the newest <=8
// outstanding loads are tile T+2's, so vmcnt(8) guarantees tile T's data without
// draining. vmcnt(0) only at the last tile. XOR-8 chunk swizzle (0 conflicts
// verified): phys 16B-chunk = logical ^ (row&7); inverse applied on global src.
template <int MODE>  // 0: out bf16 ldc=N, bias   1: out f32 ldc=N, bias+resid
__global__ __launch_bounds__(512, 2) void gemm256(
    const short* __restrict__ A, const short* __restrict__ W,
    const float* __restrict__ bias, const float* __restrict__ resid,
    void* __restrict__ Cptr, int N) {
  __shared__ __align__(16) short lds[65536];  // A: [0,32768), B: [32768,65536)

  const int tid = threadIdx.x;
  const int w = tid >> 6, l = tid & 63;
  const int wr = w >> 2, wc = w & 3;
  const int r0 = l & 15, hk = l >> 4;

  // XCD swizzle (grid % 8 == 0 here)
  const int q8 = gridDim.x >> 3;
  const int wg = (blockIdx.x & 7) * q8 + (blockIdx.x >> 3);
  const int nbx = N >> 8;
  const int mb = wg / nbx, nb = wg - mb * nbx;
  const int m0 = mb << 8, n0 = nb << 8;

  // staging: half-tile = 128 rows x 64 shorts (16KB) = 2 gload16/thread.
  const int srow = tid >> 3;                               // 0..63
  const int colsh = (((tid & 7) ^ (srow & 7)) << 3);       // inv-swizzled col (shorts)
  const short* gA00 = A + (size_t)(m0 + srow) * 1024 + colsh;
  const short* gA01 = A + (size_t)(m0 + srow + 64) * 1024 + colsh;
  const short* gA10 = A + (size_t)(m0 + 128 + srow) * 1024 + colsh;
  const short* gA11 = A + (size_t)(m0 + 128 + srow + 64) * 1024 + colsh;
  const short* gB00 = W + (size_t)(n0 + srow) * 1024 + colsh;
  const short* gB01 = W + (size_t)(n0 + srow + 64) * 1024 + colsh;
  const short* gB10 = W + (size_t)(n0 + 128 + srow) * 1024 + colsh;
  const short* gB11 = W + (size_t)(n0 + 128 + srow + 64) * 1024 + colsh;
  const int wofs = w * 512;  // wave-uniform LDS dest (shorts)

#define STAGE_A(T, BUF) do { const int kofs_ = (T) * 64, qb_ = (BUF) * 16384;       \
    gload16(gA00 + kofs_, &lds[qb_ + wofs]);                                        \
    gload16(gA01 + kofs_, &lds[qb_ + wofs + 4096]);                                 \
    gload16(gA10 + kofs_, &lds[qb_ + 8192 + wofs]);                                 \
    gload16(gA11 + kofs_, &lds[qb_ + 8192 + wofs + 4096]); } while (0)
#define STAGE_B(T, BUF) do { const int kofs_ = (T) * 64, qb_ = (BUF) * 16384;       \
    gload16(gB00 + kofs_, &lds[32768 + qb_ + wofs]);                                \
    gload16(gB01 + kofs_, &lds[32768 + qb_ + wofs + 4096]);                         \
    gload16(gB10 + kofs_, &lds[32768 + qb_ + 8192 + wofs]);                         \
    gload16(gB11 + kofs_, &lds[32768 + qb_ + 8192 + wofs + 4096]); } while (0)

  // fragment read offsets (shorts); physical chunk = (ks*4+hk) ^ (r0&7)
  const int ps0 = hk ^ (r0 & 7);
  const int aO0 = r0 * 64 + ps0 * 8;
  const int aO1 = r0 * 64 + (ps0 ^ 4) * 8;
  const int rB = (wc & 1) * 64;
  const int bO0 = (rB + r0) * 64 + ps0 * 8;
  const int bO1 = (rB + r0) * 64 + (ps0 ^ 4) * 8;
  const short* Abase = &lds[wr * 8192];                   // + buf*16384
  const short* Bbase = &lds[32768 + (wc >> 1) * 8192];    // + buf*16384

  f32x4 acc[8][4];
#pragma unroll
  for (int i = 0; i < 8; ++i)
#pragma unroll
    for (int j = 0; j < 4; ++j) acc[i][j] = (f32x4)(0.f);

  // prologue: tile 0 -> buf 0 (oldest 8), tile 1 -> buf 1
  STAGE_A(0, 0); STAGE_B(0, 0);
  STAGE_A(1, 1); STAGE_B(1, 1);

#pragma unroll 2
  for (int t = 0; t < 16; ++t) {
    const int p = t & 1;
    const short* Ab = Abase + p * 16384;
    const short* Bb = Bbase + p * 16384;
    short8 av[4][2], bw[4][2];

    // ===== P1: (i 0..3, j 0..1); vmcnt(8) = tile t's loads done, t+2's may fly =====
    __builtin_amdgcn_sched_barrier(0);
    if (t == 15) { asm volatile("s_waitcnt vmcnt(0)" ::: "memory"); }
    else         { asm volatile("s_waitcnt vmcnt(8)" ::: "memory"); }
    __builtin_amdgcn_s_barrier();
    __builtin_amdgcn_sched_barrier(0);
#pragma unroll
    for (int i4 = 0; i4 < 4; ++i4) {
      av[i4][0] = *(const short8*)&Ab[aO0 + i4 * 1024];
      av[i4][1] = *(const short8*)&Ab[aO1 + i4 * 1024];
    }
#pragma unroll
    for (int j = 0; j < 2; ++j) {
      bw[j][0] = *(const short8*)&Bb[bO0 + j * 1024];
      bw[j][1] = *(const short8*)&Bb[bO1 + j * 1024];
    }
    __builtin_amdgcn_s_setprio(1);
#pragma unroll
    for (int ks = 0; ks < 2; ++ks)
#pragma unroll
      for (int i4 = 0; i4 < 4; ++i4)
#pragma unroll
        for (int j = 0; j < 2; ++j)
          acc[i4][j] = __builtin_amdgcn_mfma_f32_16x16x32_bf16(av[i4][ks], bw[j][ks], acc[i4][j], 0, 0, 0);
    __builtin_amdgcn_s_setprio(0);

    // ===== P2: (i 0..3, j 2..3) =====
    __builtin_amdgcn_s_barrier();
    __builtin_amdgcn_sched_barrier(0);
#pragma unroll
    for (int j = 2; j < 4; ++j) {
      bw[j][0] = *(const short8*)&Bb[bO0 + j * 1024];
      bw[j][1] = *(const short8*)&Bb[bO1 + j * 1024];
    }
    __builtin_amdgcn_s_setprio(1);
#pragma unroll
    for (int ks = 0; ks < 2; ++ks)
#pragma unroll
      for (int i4 = 0; i4 < 4; ++i4)
#pragma unroll
        for (int j = 2; j < 4; ++j)
          acc[i4][j] = __builtin_amdgcn_mfma_f32_16x16x32_bf16(av[i4][ks], bw[j][ks], acc[i4][j], 0, 0, 0);
    __builtin_amdgcn_s_setprio(0);

    // ===== P3: (i 4..7, j 2..3); B of buf p is dead -> stage B(t+2) =====
    __builtin_amdgcn_s_barrier();
    __builtin_amdgcn_sched_barrier(0);
#pragma unroll
    for (int i4 = 0; i4 < 4; ++i4) {
      av[i4][0] = *(const short8*)&Ab[aO0 + (4 + i4) * 1024];
      av[i4][1] = *(const short8*)&Ab[aO1 + (4 + i4) * 1024];
    }
    if (t < 14) STAGE_B(t + 2, p);
    __builtin_amdgcn_s_setprio(1);
#pragma unroll
    for (int ks = 0; ks < 2; ++ks)
#pragma unroll
      for (int i4 = 0; i4 < 4; ++i4)
#pragma unroll
        for (int j = 2; j < 4; ++j)
          acc[4 + i4][j] = __builtin_amdgcn_mfma_f32_16x16x32_bf16(av[i4][ks], bw[j][ks], acc[4 + i4][j], 0, 0, 0);
    __builtin_amdgcn_s_setprio(0);

    // ===== P4: (i 4..7, j 0..1); A of buf p is dead -> stage A(t+2) =====
    __builtin_amdgcn_s_barrier();
    __builtin_amdgcn_sched_barrier(0);
    if (t < 14) STAGE_A(t + 2, p);
    __builtin_amdgcn_s_setprio(1);
#pragma unroll
    for (int ks = 0; ks < 2; ++ks)
#pragma unroll
      for (int i4 = 0; i4 < 4; ++i4)
#pragma unroll
        for (int j = 0; j < 2; ++j)
          acc[4 + i4][j] = __builtin_amdgcn_mfma_f32_16x16x32_bf16(av[i4][ks], bw[j][ks], acc[4 + i4][j], 0, 0, 0);
    __builtin_amdgcn_s_setprio(0);
  }
#undef STAGE_A
#undef STAGE_B

  const int crow = m0 + wr * 128 + hk * 4;
  const int ccol = n0 + wc * 64 + r0;
  if (MODE == 0) {
    short* C = (short*)Cptr;
#pragma unroll
    for (int j = 0; j < 4; ++j) {
      float bj = bias[ccol + j * 16];
#pragma unroll
      for (int i = 0; i < 8; ++i) {
        size_t base = (size_t)(crow + i * 16) * N + (ccol + j * 16);
#pragma unroll
        for (int rr = 0; rr < 4; ++rr)
          C[base + (size_t)rr * N] = f2b(acc[i][j][rr] + bj);
      }
    }
  } else {
    float* C = (float*)Cptr;
#pragma unroll
    for (int j = 0; j < 4; ++j) {
      float bj = bias[ccol + j * 16];
#pragma unroll
      for (int i = 0; i < 8; ++i) {
        size_t base = (size_t)(crow + i * 16) * N + (ccol + j * 16);
#pragma unroll
        for (int rr = 0; rr < 4; ++rr)
          C[base + (size_t)rr * N] =
              acc[i][j][rr] + bj + resid[base + (size_t)rr * N];
      }
    }
  }
}

// ---------------- attention: 1 block per b, 4 waves, 2 heads/wave ----------------
__global__ __launch_bounds__(256) void attn_kernel(
    const short* __restrict__ qkv, const float* __restrict__ prior,
    const float* __restrict__ mask, short* __restrict__ out) {
  __shared__ short sq[8 * 3080];  // rows padded +8 shorts to break bank conflicts
  const int tid = threadIdx.x;
  const int b = blockIdx.x;
  for (int c = tid; c < 3072; c += 256) {
    int row = c / 384;
    int cc = c - row * 384;
    *(short8*)&sq[row * 3080 + cc * 8] =
        *(const short8*)&qkv[((size_t)b * 8 + row) * 3072 + cc * 8];
  }
  __syncthreads();
  const int l = tid & 63, w = tid >> 6;
  const int i = l >> 3, j = l & 7;
  const float pv = prior[l];
  const float mm = mask[b * 8 + i] * mask[b * 8 + j];
#pragma unroll
  for (int hh = 0; hh < 2; ++hh) {
    const int h = w + hh * 4;
    const short* Qr = &sq[i * 3080 + h * 128];
    const short* Kr = &sq[j * 3080 + 1024 + h * 128];
    float s = 0.f;
#pragma unroll
    for (int c = 0; c < 16; ++c) {
      short8 qa = *(const short8*)&Qr[c * 8];
      short8 ka = *(const short8*)&Kr[c * 8];
#pragma unroll
      for (int e = 0; e < 8; ++e) s += bf2f(qa[e]) * bf2f(ka[e]);
    }
    s = s * 0.08838834764831843f + pv;  // 1/sqrt(128)
    if (!(mm > 0.f)) s = -__builtin_inff();
    float mx = s;
#pragma unroll
    for (int off = 1; off < 8; off <<= 1) mx = fmaxf(mx, __shfl_xor(mx, off));
    float e = __expf(s - mx);
    float sum = e;
#pragma unroll
    for (int off = 1; off < 8; off <<= 1) sum += __shfl_xor(sum, off);
    float p = e / sum;
    float o[16];
#pragma unroll
    for (int t = 0; t < 16; ++t) o[t] = 0.f;
#pragma unroll
    for (int jj = 0; jj < 8; ++jj) {
      float pj = __shfl(p, i * 8 + jj);
      const short* Vr = &sq[jj * 3080 + 2048 + h * 128 + j * 16];
      short8 v0 = *(const short8*)&Vr[0];
      short8 v1 = *(const short8*)&Vr[8];
#pragma unroll
      for (int e2 = 0; e2 < 8; ++e2) {
        o[e2] += pj * bf2f(v0[e2]);
        o[8 + e2] += pj * bf2f(v1[e2]);
      }
    }
    short8 o0, o1;
#pragma unroll
    for (int e2 = 0; e2 < 8; ++e2) { o0[e2] = f2b(o[e2]); o1[e2] = f2b(o[8 + e2]); }
    short* dst = out + ((size_t)(b * 8 + i)) * 1024 + h * 128 + j * 16;
    *(short8*)dst = o0;
    *(short8*)(dst + 8) = o1;
  }
}

// ---------------- LayerNorm in-place, 1 wave per row ----------------
__global__ __launch_bounds__(256) void ln_kernel(float* __restrict__ io,
                                                 const float* __restrict__ gamma,
                                                 const float* __restrict__ beta) {
  const int l = threadIdx.x & 63, w = threadIdx.x >> 6;
  float* p = io + ((size_t)blockIdx.x * 4 + w) * 1024;
  f32x4 v[4];
  float s = 0.f;
#pragma unroll
  for (int c = 0; c < 4; ++c) {
    v[c] = *(const f32x4*)(p + (c * 64 + l) * 4);
    s += v[c][0] + v[c][1] + v[c][2] + v[c][3];
  }
#pragma unroll
  for (int off = 32; off > 0; off >>= 1) s += __shfl_xor(s, off);
  const float mu = s * (1.f / 1024.f);
  float s2 = 0.f;
#pragma unroll
  for (int c = 0; c < 4; ++c)
#pragma unroll
    for (int e = 0; e < 4; ++e) { float d = v[c][e] - mu; s2 += d * d; }
#pragma unroll
  for (int off = 32; off > 0; off >>= 1) s2 += __shfl_xor(s2, off);
  const float rstd = rsqrtf(s2 * (1.f / 1024.f) + LN_EPS);
#pragma unroll
  for (int c = 0; c < 4; ++c) {
    f32x4 g = *(const f32x4*)(gamma + (c * 64 + l) * 4);
    f32x4 bt = *(const f32x4*)(beta + (c * 64 + l) * 4);
    f32x4 ov;
#pragma unroll
    for (int e = 0; e < 4; ++e) ov[e] = (v[c][e] - mu) * rstd * g[e] + bt[e];
    *(f32x4*)(p + (c * 64 + l) * 4) = ov;
  }
}

extern "C" void kernel_launch(void* const* d_in, const int* in_sizes, int n_in,
                              void* d_out, int out_size, void* d_ws, size_t ws_size,
                              hipStream_t stream) {
  const float* x     = (const float*)d_in[0];
  const float* mask  = (const float*)d_in[1];
  const float* wq    = (const float*)d_in[2];
  const float* bq    = (const float*)d_in[3];
  const float* wk    = (const float*)d_in[4];
  const float* bk    = (const float*)d_in[5];
  const float* wv    = (const float*)d_in[6];
  const float* bv    = (const float*)d_in[7];
  const float* wo    = (const float*)d_in[8];
  const float* bo    = (const float*)d_in[9];
  const float* prior = (const float*)d_in[10];
  const float* gamma = (const float*)d_in[11];
  const float* beta  = (const float*)d_in[12];

  char* ws = (char*)d_ws;
  short* qkv  = (short*)(ws);                    // [65536][3072] bf16 (402.7 MB)
  short* xb   = (short*)(ws + 402653184L);       // [65536][1024] bf16; reused as attn_out
  short* wall = (short*)(ws + 536870912L);       // [3072][1024] bf16 (Wq|Wk|Wv)
  short* wob  = (short*)(ws + 543162368L);       // [1024][1024] bf16
  float* ball = (float*)(ws + 545259520L);       // [3072] f32

  cvt_kernel<<<2048, 256, 0, stream>>>(x, xb, 8388608);
  cvt_w_kernel<<<2048, 256, 0, stream>>>(wq, wk, wv, wo, wall, wob);
  pack_bias<<<4, 256, 0, stream>>>(bq, bk, bv, ball);

  // QKV projection: [65536,3072] = xb @ Wall^T + ball   (256x12 = 3072 blocks)
  gemm256<0><<<3072, 512, 0, stream>>>(xb, wall, ball, nullptr, qkv, 3072);
  // attention (writes into xb, free after QKV GEMM)
  attn_kernel<<<8192, 256, 0, stream>>>(qkv, prior, mask, xb);
  // O projection + bias + residual -> d_out (f32)   (256x4 = 1024 blocks)
  gemm256<1><<<1024, 512, 0, stream>>>(xb, wob, bo, x, d_out, 1024);
  // LayerNorm in-place on d_out
  ln_kernel<<<16384, 256, 0, stream>>>((float*)d_out, gamma, beta);
}

// Round 11
// 896.366 us; speedup vs baseline: 7.6659x; 1.0713x over previous
//
#include <hip/hip_runtime.h>

typedef __attribute__((ext_vector_type(4))) float f32x4;
typedef __attribute__((ext_vector_type(8))) short short8;
typedef __attribute__((ext_vector_type(4))) short short4v;

#define LN_EPS 1e-5f

__device__ __forceinline__ float bf2f(short x) {
  union { unsigned u; float f; } c;
  c.u = ((unsigned)(unsigned short)x) << 16;
  return c.f;
}
__device__ __forceinline__ short f2b(float f) {
  union { float f; unsigned u; } c; c.f = f;
  unsigned r = (c.u + 0x7fffu + ((c.u >> 16) & 1u)) >> 16;
  return (short)r;
}

// ---------------- f32 -> bf16 convert (8 elems / thread) ----------------
__global__ __launch_bounds__(256) void cvt_kernel(const float* __restrict__ src,
                                                  short* __restrict__ dst, int n8) {
  int idx = blockIdx.x * 256 + threadIdx.x;
  int stride = gridDim.x * 256;
  for (int c = idx; c < n8; c += stride) {
    const f32x4* s = (const f32x4*)(src + (size_t)c * 8);
    f32x4 v0 = s[0], v1 = s[1];
    short8 o;
    o[0] = f2b(v0.x); o[1] = f2b(v0.y); o[2] = f2b(v0.z); o[3] = f2b(v0.w);
    o[4] = f2b(v1.x); o[5] = f2b(v1.y); o[6] = f2b(v1.z); o[7] = f2b(v1.w);
    *(short8*)(dst + (size_t)c * 8) = o;
  }
}

// all 4 weight matrices in one launch: 4 x 131072 chunks of 8
__global__ __launch_bounds__(256) void cvt_w_kernel(
    const float* __restrict__ wq, const float* __restrict__ wk,
    const float* __restrict__ wv, const float* __restrict__ wo,
    short* __restrict__ wall, short* __restrict__ wob) {
  int c = blockIdx.x * 256 + threadIdx.x;
  int stride = gridDim.x * 256;
  for (; c < 524288; c += stride) {
    int seg = c >> 17, idx = c & 131071;
    const float* src = (seg == 0) ? wq : (seg == 1) ? wk : (seg == 2) ? wv : wo;
    short* dst = (seg == 3) ? wob : (wall + (size_t)seg * 1048576);
    const f32x4* s = (const f32x4*)(src + (size_t)idx * 8);
    f32x4 v0 = s[0], v1 = s[1];
    short8 o;
    o[0] = f2b(v0.x); o[1] = f2b(v0.y); o[2] = f2b(v0.z); o[3] = f2b(v0.w);
    o[4] = f2b(v1.x); o[5] = f2b(v1.y); o[6] = f2b(v1.z); o[7] = f2b(v1.w);
    *(short8*)(dst + (size_t)idx * 8) = o;
  }
}

__global__ __launch_bounds__(256) void pack_bias(const float* __restrict__ bq,
                                                 const float* __restrict__ bk,
                                                 const float* __restrict__ bv,
                                                 float* __restrict__ dst) {
  int t = blockIdx.x * 256 + threadIdx.x;
  if (t < 1024) { dst[t] = bq[t]; dst[1024 + t] = bk[t]; dst[2048 + t] = bv[t]; }
}

__device__ __forceinline__ void gload16(const short* g, const short* l) {
  __builtin_amdgcn_global_load_lds((const __attribute__((address_space(1))) unsigned int*)g,
                                   (__attribute__((address_space(3))) unsigned int*)l,
                                   16, 0, 0);
}

// ---------------- GEMM: C[M,N] = A[M,1024] * W[N,1024]^T + bias, out bf16 ----------
// r4/r10 structure (best measured: 43% MfmaUtil): 256x256 tile, BK=64, 512 threads
// (8 waves 2Mx4N), LDS = 2dbuf x {A,B} x 16KB = 128KB. 4 phases per K-tile; counted
// vmcnt(8) ledger: during tile T stage tile T+2 into T's own buffer, B-halves at P3
// (dead after P2 reads), A-halves at P4 (dead after P3). At P1 the newest <=8
// outstanding loads are tile T+2's, so vmcnt(8) guarantees tile T's data without
// draining. vmcnt(0) only at the last tile. XOR-8 chunk swizzle (0 conflicts
// verified): phys 16B-chunk = logical ^ (row&7); inverse applied on global src.
__global__ __launch_bounds__(512, 2) void gemm256(
    const short* __restrict__ A, const short* __restrict__ W,
    const float* __restrict__ bias, short* __restrict__ C, int N) {
  __shared__ __align__(16) short lds[65536];  // A: [0,32768), B: [32768,65536)

  const int tid = threadIdx.x;
  const int w = tid >> 6, l = tid & 63;
  const int wr = w >> 2, wc = w & 3;
  const int r0 = l & 15, hk = l >> 4;

  // XCD swizzle (grid % 8 == 0 here)
  const int q8 = gridDim.x >> 3;
  const int wg = (blockIdx.x & 7) * q8 + (blockIdx.x >> 3);
  const int nbx = N >> 8;
  const int mb = wg / nbx, nb = wg - mb * nbx;
  const int m0 = mb << 8, n0 = nb << 8;

  // staging: half-tile = 128 rows x 64 shorts (16KB) = 2 gload16/thread.
  const int srow = tid >> 3;                               // 0..63
  const int colsh = (((tid & 7) ^ (srow & 7)) << 3);       // inv-swizzled col (shorts)
  const short* gA00 = A + (size_t)(m0 + srow) * 1024 + colsh;
  const short* gA01 = A + (size_t)(m0 + srow + 64) * 1024 + colsh;
  const short* gA10 = A + (size_t)(m0 + 128 + srow) * 1024 + colsh;
  const short* gA11 = A + (size_t)(m0 + 128 + srow + 64) * 1024 + colsh;
  const short* gB00 = W + (size_t)(n0 + srow) * 1024 + colsh;
  const short* gB01 = W + (size_t)(n0 + srow + 64) * 1024 + colsh;
  const short* gB10 = W + (size_t)(n0 + 128 + srow) * 1024 + colsh;
  const short* gB11 = W + (size_t)(n0 + 128 + srow + 64) * 1024 + colsh;
  const int wofs = w * 512;  // wave-uniform LDS dest (shorts)

#define STAGE_A(T, BUF) do { const int kofs_ = (T) * 64, qb_ = (BUF) * 16384;       \
    gload16(gA00 + kofs_, &lds[qb_ + wofs]);                                        \
    gload16(gA01 + kofs_, &lds[qb_ + wofs + 4096]);                                 \
    gload16(gA10 + kofs_, &lds[qb_ + 8192 + wofs]);                                 \
    gload16(gA11 + kofs_, &lds[qb_ + 8192 + wofs + 4096]); } while (0)
#define STAGE_B(T, BUF) do { const int kofs_ = (T) * 64, qb_ = (BUF) * 16384;       \
    gload16(gB00 + kofs_, &lds[32768 + qb_ + wofs]);                                \
    gload16(gB01 + kofs_, &lds[32768 + qb_ + wofs + 4096]);                         \
    gload16(gB10 + kofs_, &lds[32768 + qb_ + 8192 + wofs]);                         \
    gload16(gB11 + kofs_, &lds[32768 + qb_ + 8192 + wofs + 4096]); } while (0)

  // fragment read offsets (shorts); physical chunk = (ks*4+hk) ^ (r0&7)
  const int ps0 = hk ^ (r0 & 7);
  const int aO0 = r0 * 64 + ps0 * 8;
  const int aO1 = r0 * 64 + (ps0 ^ 4) * 8;
  const int rB = (wc & 1) * 64;
  const int bO0 = (rB + r0) * 64 + ps0 * 8;
  const int bO1 = (rB + r0) * 64 + (ps0 ^ 4) * 8;
  const short* Abase = &lds[wr * 8192];                   // + buf*16384
  const short* Bbase = &lds[32768 + (wc >> 1) * 8192];    // + buf*16384

  f32x4 acc[8][4];
#pragma unroll
  for (int i = 0; i < 8; ++i)
#pragma unroll
    for (int j = 0; j < 4; ++j) acc[i][j] = (f32x4)(0.f);

  // prologue: tile 0 -> buf 0 (oldest 8), tile 1 -> buf 1
  STAGE_A(0, 0); STAGE_B(0, 0);
  STAGE_A(1, 1); STAGE_B(1, 1);

#pragma unroll 2
  for (int t = 0; t < 16; ++t) {
    const int p = t & 1;
    const short* Ab = Abase + p * 16384;
    const short* Bb = Bbase + p * 16384;
    short8 av[4][2], bw[4][2];

    // ===== P1: (i 0..3, j 0..1); vmcnt(8) = tile t's loads done, t+2's may fly =====
    __builtin_amdgcn_sched_barrier(0);
    if (t == 15) { asm volatile("s_waitcnt vmcnt(0)" ::: "memory"); }
    else         { asm volatile("s_waitcnt vmcnt(8)" ::: "memory"); }
    __builtin_amdgcn_s_barrier();
    __builtin_amdgcn_sched_barrier(0);
#pragma unroll
    for (int i4 = 0; i4 < 4; ++i4) {
      av[i4][0] = *(const short8*)&Ab[aO0 + i4 * 1024];
      av[i4][1] = *(const short8*)&Ab[aO1 + i4 * 1024];
    }
#pragma unroll
    for (int j = 0; j < 2; ++j) {
      bw[j][0] = *(const short8*)&Bb[bO0 + j * 1024];
      bw[j][1] = *(const short8*)&Bb[bO1 + j * 1024];
    }
    __builtin_amdgcn_s_setprio(1);
#pragma unroll
    for (int ks = 0; ks < 2; ++ks)
#pragma unroll
      for (int i4 = 0; i4 < 4; ++i4)
#pragma unroll
        for (int j = 0; j < 2; ++j)
          acc[i4][j] = __builtin_amdgcn_mfma_f32_16x16x32_bf16(av[i4][ks], bw[j][ks], acc[i4][j], 0, 0, 0);
    __builtin_amdgcn_s_setprio(0);

    // ===== P2: (i 0..3, j 2..3) =====
    __builtin_amdgcn_s_barrier();
    __builtin_amdgcn_sched_barrier(0);
#pragma unroll
    for (int j = 2; j < 4; ++j) {
      bw[j][0] = *(const short8*)&Bb[bO0 + j * 1024];
      bw[j][1] = *(const short8*)&Bb[bO1 + j * 1024];
    }
    __builtin_amdgcn_s_setprio(1);
#pragma unroll
    for (int ks = 0; ks < 2; ++ks)
#pragma unroll
      for (int i4 = 0; i4 < 4; ++i4)
#pragma unroll
        for (int j = 2; j < 4; ++j)
          acc[i4][j] = __builtin_amdgcn_mfma_f32_16x16x32_bf16(av[i4][ks], bw[j][ks], acc[i4][j], 0, 0, 0);
    __builtin_amdgcn_s_setprio(0);

    // ===== P3: (i 4..7, j 2..3); B of buf p is dead -> stage B(t+2) =====
    __builtin_amdgcn_s_barrier();
    __builtin_amdgcn_sched_barrier(0);
#pragma unroll
    for (int i4 = 0; i4 < 4; ++i4) {
      av[i4][0] = *(const short8*)&Ab[aO0 + (4 + i4) * 1024];
      av[i4][1] = *(const short8*)&Ab[aO1 + (4 + i4) * 1024];
    }
    if (t < 14) STAGE_B(t + 2, p);
    __builtin_amdgcn_s_setprio(1);
#pragma unroll
    for (int ks = 0; ks < 2; ++ks)
#pragma unroll
      for (int i4 = 0; i4 < 4; ++i4)
#pragma unroll
        for (int j = 2; j < 4; ++j)
          acc[4 + i4][j] = __builtin_amdgcn_mfma_f32_16x16x32_bf16(av[i4][ks], bw[j][ks], acc[4 + i4][j], 0, 0, 0);
    __builtin_amdgcn_s_setprio(0);

    // ===== P4: (i 4..7, j 0..1); A of buf p is dead -> stage A(t+2) =====
    __builtin_amdgcn_s_barrier();
    __builtin_amdgcn_sched_barrier(0);
    if (t < 14) STAGE_A(t + 2, p);
    __builtin_amdgcn_s_setprio(1);
#pragma unroll
    for (int ks = 0; ks < 2; ++ks)
#pragma unroll
      for (int i4 = 0; i4 < 4; ++i4)
#pragma unroll
        for (int j = 0; j < 2; ++j)
          acc[4 + i4][j] = __builtin_amdgcn_mfma_f32_16x16x32_bf16(av[i4][ks], bw[j][ks], acc[4 + i4][j], 0, 0, 0);
    __builtin_amdgcn_s_setprio(0);
  }
#undef STAGE_A
#undef STAGE_B

  const int crow = m0 + wr * 128 + hk * 4;
  const int ccol = n0 + wc * 64 + r0;
#pragma unroll
  for (int j = 0; j < 4; ++j) {
    float bj = bias[ccol + j * 16];
#pragma unroll
    for (int i = 0; i < 8; ++i) {
      size_t base = (size_t)(crow + i * 16) * N + (ccol + j * 16);
#pragma unroll
      for (int rr = 0; rr < 4; ++rr)
        C[base + (size_t)rr * N] = f2b(acc[i][j][rr] + bj);
    }
  }
}

// ---------------- attention: 1 block per b, 4 waves, 2 heads/wave ----------------
__global__ __launch_bounds__(256) void attn_kernel(
    const short* __restrict__ qkv, const float* __restrict__ prior,
    const float* __restrict__ mask, short* __restrict__ out) {
  __shared__ short sq[8 * 3080];  // rows padded +8 shorts to break bank conflicts
  const int tid = threadIdx.x;
  const int b = blockIdx.x;
  for (int c = tid; c < 3072; c += 256) {
    int row = c / 384;
    int cc = c - row * 384;
    *(short8*)&sq[row * 3080 + cc * 8] =
        *(const short8*)&qkv[((size_t)b * 8 + row) * 3072 + cc * 8];
  }
  __syncthreads();
  const int l = tid & 63, w = tid >> 6;
  const int i = l >> 3, j = l & 7;
  const float pv = prior[l];
  const float mm = mask[b * 8 + i] * mask[b * 8 + j];
#pragma unroll
  for (int hh = 0; hh < 2; ++hh) {
    const int h = w + hh * 4;
    const short* Qr = &sq[i * 3080 + h * 128];
    const short* Kr = &sq[j * 3080 + 1024 + h * 128];
    float s = 0.f;
#pragma unroll
    for (int c = 0; c < 16; ++c) {
      short8 qa = *(const short8*)&Qr[c * 8];
      short8 ka = *(const short8*)&Kr[c * 8];
#pragma unroll
      for (int e = 0; e < 8; ++e) s += bf2f(qa[e]) * bf2f(ka[e]);
    }
    s = s * 0.08838834764831843f + pv;  // 1/sqrt(128)
    if (!(mm > 0.f)) s = -__builtin_inff();
    float mx = s;
#pragma unroll
    for (int off = 1; off < 8; off <<= 1) mx = fmaxf(mx, __shfl_xor(mx, off));
    float e = __expf(s - mx);
    float sum = e;
#pragma unroll
    for (int off = 1; off < 8; off <<= 1) sum += __shfl_xor(sum, off);
    float p = e / sum;
    float o[16];
#pragma unroll
    for (int t = 0; t < 16; ++t) o[t] = 0.f;
#pragma unroll
    for (int jj = 0; jj < 8; ++jj) {
      float pj = __shfl(p, i * 8 + jj);
      const short* Vr = &sq[jj * 3080 + 2048 + h * 128 + j * 16];
      short8 v0 = *(const short8*)&Vr[0];
      short8 v1 = *(const short8*)&Vr[8];
#pragma unroll
      for (int e2 = 0; e2 < 8; ++e2) {
        o[e2] += pj * bf2f(v0[e2]);
        o[8 + e2] += pj * bf2f(v1[e2]);
      }
    }
    short8 o0, o1;
#pragma unroll
    for (int e2 = 0; e2 < 8; ++e2) { o0[e2] = f2b(o[e2]); o1[e2] = f2b(o[8 + e2]); }
    short* dst = out + ((size_t)(b * 8 + i)) * 1024 + h * 128 + j * 16;
    *(short8*)dst = o0;
    *(short8*)(dst + 8) = o1;
  }
}

// ---------- LayerNorm fused with residual: out = LN(x + po) * gamma + beta ----------
// 1 wave per row; po is bf16 projection output (bias already added in GEMM epilogue).
__global__ __launch_bounds__(256) void ln_fused(
    const short* __restrict__ po, const float* __restrict__ x,
    const float* __restrict__ gamma, const float* __restrict__ beta,
    float* __restrict__ out) {
  const int l = threadIdx.x & 63, w = threadIdx.x >> 6;
  const size_t row = (size_t)blockIdx.x * 4 + w;
  const float* xp = x + row * 1024;
  const short* pp = po + row * 1024;
  float* op = out + row * 1024;
  f32x4 v[4];
  float s = 0.f;
#pragma unroll
  for (int c = 0; c < 4; ++c) {
    f32x4 xa = *(const f32x4*)(xp + (c * 64 + l) * 4);
    short4v pa = *(const short4v*)(pp + (c * 64 + l) * 4);
#pragma unroll
    for (int e = 0; e < 4; ++e) v[c][e] = xa[e] + bf2f(pa[e]);
    s += v[c][0] + v[c][1] + v[c][2] + v[c][3];
  }
#pragma unroll
  for (int off = 32; off > 0; off >>= 1) s += __shfl_xor(s, off);
  const float mu = s * (1.f / 1024.f);
  float s2 = 0.f;
#pragma unroll
  for (int c = 0; c < 4; ++c)
#pragma unroll
    for (int e = 0; e < 4; ++e) { float d = v[c][e] - mu; s2 += d * d; }
#pragma unroll
  for (int off = 32; off > 0; off >>= 1) s2 += __shfl_xor(s2, off);
  const float rstd = rsqrtf(s2 * (1.f / 1024.f) + LN_EPS);
#pragma unroll
  for (int c = 0; c < 4; ++c) {
    f32x4 g = *(const f32x4*)(gamma + (c * 64 + l) * 4);
    f32x4 bt = *(const f32x4*)(beta + (c * 64 + l) * 4);
    f32x4 ov;
#pragma unroll
    for (int e = 0; e < 4; ++e) ov[e] = (v[c][e] - mu) * rstd * g[e] + bt[e];
    *(f32x4*)(op + (c * 64 + l) * 4) = ov;
  }
}

extern "C" void kernel_launch(void* const* d_in, const int* in_sizes, int n_in,
                              void* d_out, int out_size, void* d_ws, size_t ws_size,
                              hipStream_t stream) {
  const float* x     = (const float*)d_in[0];
  const float* mask  = (const float*)d_in[1];
  const float* wq    = (const float*)d_in[2];
  const float* bq    = (const float*)d_in[3];
  const float* wk    = (const float*)d_in[4];
  const float* bk    = (const float*)d_in[5];
  const float* wv    = (const float*)d_in[6];
  const float* bv    = (const float*)d_in[7];
  const float* wo    = (const float*)d_in[8];
  const float* bo    = (const float*)d_in[9];
  const float* prior = (const float*)d_in[10];
  const float* gamma = (const float*)d_in[11];
  const float* beta  = (const float*)d_in[12];

  char* ws = (char*)d_ws;
  short* qkv  = (short*)(ws);                    // [65536][3072] bf16 (402.7 MB)
  short* po   = (short*)(ws);                    // [65536][1024] bf16 — reuses dead qkv
  short* xb   = (short*)(ws + 402653184L);       // [65536][1024] bf16; reused as attn_out
  short* wall = (short*)(ws + 536870912L);       // [3072][1024] bf16 (Wq|Wk|Wv)
  short* wob  = (short*)(ws + 543162368L);       // [1024][1024] bf16
  float* ball = (float*)(ws + 545259520L);       // [3072] f32

  cvt_kernel<<<2048, 256, 0, stream>>>(x, xb, 8388608);
  cvt_w_kernel<<<2048, 256, 0, stream>>>(wq, wk, wv, wo, wall, wob);
  pack_bias<<<4, 256, 0, stream>>>(bq, bk, bv, ball);

  // QKV projection: [65536,3072] = xb @ Wall^T + ball   (256x12 = 3072 blocks)
  gemm256<<<3072, 512, 0, stream>>>(xb, wall, ball, qkv, 3072);
  // attention (writes into xb, free after QKV GEMM)
  attn_kernel<<<8192, 256, 0, stream>>>(qkv, prior, mask, xb);
  // O projection + bias -> bf16 po (qkv region is dead now)
  gemm256<<<1024, 512, 0, stream>>>(xb, wob, bo, po, 1024);
  // LayerNorm fused with f32 residual -> d_out
  ln_fused<<<16384, 256, 0, stream>>>(po, x, gamma, beta, (float*)d_out);
}